// Round 5
// baseline (490.289 us; speedup 1.0000x reference)
//
#include <hip/hip_runtime.h>
#include <math.h>

// RegionalGNN: B=8192, NC=8, H=256, HD=1024, L=3.
// R5: full per-layer fusion. k_layer = GEMM1(X@Wqk) + 8x8 attention + GEMM2(y@Wvo)
//     + residual + LayerNorm in ONE kernel; T lives in LDS; X traffic per layer
//     drops from ~200MB to ~67MB. k_attn/k_gemmW<2> removed. Final head split into
//     streaming GDP-reduce + small GEMM. (R4 lesson: scalar-global residual loads +
//     grid-64 + per-k barrier drains = latency-bound 89us regardless of conflicts.)

typedef short bf16x8 __attribute__((ext_vector_type(8)));
typedef float f32x4  __attribute__((ext_vector_type(4)));

__device__ __forceinline__ float bflo(unsigned int u){ return __uint_as_float(u << 16); }
__device__ __forceinline__ float bfhi(unsigned int u){ return __uint_as_float(u & 0xffff0000u); }
__device__ __forceinline__ float bfs(short s){ return __uint_as_float((unsigned int)(unsigned short)s << 16); }
__device__ __forceinline__ unsigned short f2bf(float f){
  unsigned int u = __float_as_uint(f);
  u += 0x7fffu + ((u >> 16) & 1u);          // RNE
  return (unsigned short)(u >> 16);
}
__device__ __forceinline__ void unpack8(uint4 a, float* o){
  o[0]=bflo(a.x); o[1]=bfhi(a.x); o[2]=bflo(a.y); o[3]=bfhi(a.y);
  o[4]=bflo(a.z); o[5]=bfhi(a.z); o[6]=bflo(a.w); o[7]=bfhi(a.w);
}
__device__ __forceinline__ uint4 pack8(const float* v){
  uint4 r;
  r.x = (unsigned int)f2bf(v[0]) | ((unsigned int)f2bf(v[1]) << 16);
  r.y = (unsigned int)f2bf(v[2]) | ((unsigned int)f2bf(v[3]) << 16);
  r.z = (unsigned int)f2bf(v[4]) | ((unsigned int)f2bf(v[5]) << 16);
  r.w = (unsigned int)f2bf(v[6]) | ((unsigned int)f2bf(v[7]) << 16);
  return r;
}
__device__ __forceinline__ float dot8(uint4 a, uint4 b, float s){
  s = fmaf(bflo(a.x), bflo(b.x), s); s = fmaf(bfhi(a.x), bfhi(b.x), s);
  s = fmaf(bflo(a.y), bflo(b.y), s); s = fmaf(bfhi(a.y), bfhi(b.y), s);
  s = fmaf(bflo(a.z), bflo(b.z), s); s = fmaf(bfhi(a.z), bfhi(b.z), s);
  s = fmaf(bflo(a.w), bflo(b.w), s); s = fmaf(bfhi(a.w), bfhi(b.w), s);
  return s;
}
__device__ __forceinline__ void gload16(const void* g, void* l){
  __builtin_amdgcn_global_load_lds(
      (const __attribute__((address_space(1))) unsigned int*)g,
      (__attribute__((address_space(3))) unsigned int*)l, 16, 0, 0);
}

// ---------------- convert f32 -> bf16 (rf, Wq, Wk, Wv) ----------------
struct CvP { const float* src[4]; short* dst[4]; int boff[5]; };
__global__ __launch_bounds__(256) void k_convert(CvP p){
  int bid = blockIdx.x, s = 0;
  while (bid >= p.boff[s+1]) s++;
  size_t e = (size_t)(bid - p.boff[s]) * 2048 + (size_t)threadIdx.x * 8;
  const float* src = p.src[s] + e;
  float4 v0 = *(const float4*)src;
  float4 v1 = *(const float4*)(src + 4);
  float v[8] = {v0.x,v0.y,v0.z,v0.w,v1.x,v1.y,v1.z,v1.w};
  *(uint4*)(p.dst[s] + e) = pack8(v);
}

// ---------------- transpose + convert (Wi, Wo x3, Wp) ----------------
struct TrP { const float* src[5]; short* dst[5]; int rows[5]; int cols[5]; int toff[6]; };
__global__ __launch_bounds__(256) void k_transpose(TrP p){
  __shared__ float tile[64][65];
  int bid = blockIdx.x, s = 0;
  while (bid >= p.toff[s+1]) s++;
  int ti = bid - p.toff[s];
  int cols = p.cols[s], rows = p.rows[s];
  int ntc = cols >> 6;
  int r0 = (ti / ntc) * 64, c0 = (ti % ntc) * 64;
  const float* src = p.src[s];
  int row = threadIdx.x >> 2, jb = (threadIdx.x & 3) * 16;
  #pragma unroll
  for (int j = 0; j < 16; j += 4){
    float4 v = *(const float4*)(src + (size_t)(r0 + row) * cols + c0 + jb + j);
    tile[row][jb+j] = v.x; tile[row][jb+j+1] = v.y; tile[row][jb+j+2] = v.z; tile[row][jb+j+3] = v.w;
  }
  __syncthreads();
  short* dst = p.dst[s];
  float tmp[16];
  #pragma unroll
  for (int j = 0; j < 16; j++) tmp[j] = tile[jb + j][row];
  #pragma unroll
  for (int j = 0; j < 16; j += 8)
    *(uint4*)(dst + (size_t)(c0 + row) * rows + r0 + jb + j) = pack8(&tmp[j]);
}

// ---------------- bias-fold vectors via bf16 row-dots ----------------
__global__ __launch_bounds__(256) void k_vecs2(
    const short* Wqb, const short* Wkb, const short* WoTb,
    const float* bq, const float* bk, const float* bv, const float* bo,
    float* cq, float* ck, float* cvo, float* c0){
  const int job = blockIdx.x, l = blockIdx.y, tid = threadIdx.x;
  __shared__ float sv[1024];
  __shared__ float red[256];
  if (job == 3){
    float pp = 0.f;
    #pragma unroll
    for (int i = 0; i < 4; i++){
      int d = tid*4 + i;
      pp = fmaf(bq[l*1024 + d], bk[l*1024 + d], pp);
    }
    red[tid] = pp; __syncthreads();
    for (int o = 128; o > 0; o >>= 1){ if (tid < o) red[tid] += red[tid + o]; __syncthreads(); }
    if (tid == 0) c0[l] = red[0] * 0.0625f;
    return;
  }
  const short* rows = (job==0 ? Wqb : job==1 ? Wkb : WoTb) + (size_t)l*262144;
  const float* vecg = (job==0 ? bk : job==1 ? bq : bv) + l*1024;
  const float scale = (job == 2) ? 1.0f : 0.0625f;
  for (int i = tid; i < 1024; i += 256) sv[i] = vecg[i];
  __syncthreads();
  const int row = tid >> 3, sub = tid & 7;
  for (int pass = 0; pass < 8; pass++){
    int r = pass*32 + row;
    const short* rp = rows + (size_t)r*1024;
    float acc = 0.f;
    #pragma unroll
    for (int i = 0; i < 16; i++){
      int d = sub*8 + i*64;
      uint4 v = *(const uint4*)(rp + d);
      float f[8]; unpack8(v, f);
      #pragma unroll
      for (int j = 0; j < 8; j++) acc = fmaf(f[j], sv[d + j], acc);
    }
    acc += __shfl_xor(acc, 1); acc += __shfl_xor(acc, 2); acc += __shfl_xor(acc, 4);
    if (sub == 0){
      float o = acc * scale;
      if (job == 2) o += bo[l*256 + r];
      (job==0 ? cq : job==1 ? ck : cvo)[l*256 + r] = o;
    }
  }
}

// ---------------- 128x128 MFMA GEMM (precompute + input projection) ----------------
struct GDesc { const short* A; const short* Bt; short* C; int K; float scale; };
struct GemmP { GDesc d[6]; const float* bi; const float* emb; short* X; };
template<int MODE>
__global__ __launch_bounds__(256) void k_gemm128(GemmP p){
  GDesc g = p.d[blockIdx.z];
  const int tid = threadIdx.x, lane = tid & 63, w = tid >> 6;
  const int wm = w >> 1, wn = w & 1;
  __shared__ alignas(16) short As[128*32];
  __shared__ alignas(16) short Bs[128*32];
  __shared__ float s_bi[256];
  __shared__ float s_emb[2048];
  if constexpr (MODE == 1){
    s_bi[tid] = p.bi[tid];
    for (int i = tid; i < 2048; i += 256) s_emb[i] = p.emb[i];
  }
  const int K = g.K;
  const short* Ab = g.A + (size_t)blockIdx.x * 128 * K;
  const short* Bb = g.Bt + (size_t)blockIdx.y * 128 * K;
  f32x4 acc[4][4] = {};
  for (int k0 = 0; k0 < K; k0 += 32){
    #pragma unroll
    for (int i = 0; i < 2; i++){
      int s = w*2 + i;
      int ro = (s >> 2)*64 + (s & 3)*16 + (lane & 15);
      int co = k0 + (lane >> 4) * 8;
      gload16(Ab + (size_t)ro * K + co, &As[s*512]);
      gload16(Bb + (size_t)ro * K + co, &Bs[s*512]);
    }
    __syncthreads();
    bf16x8 av[4], bv[4];
    #pragma unroll
    for (int mi = 0; mi < 4; mi++)
      av[mi] = *(const bf16x8*)&As[((wm*4 + mi)*64 + lane)*8];
    #pragma unroll
    for (int nj = 0; nj < 4; nj++)
      bv[nj] = *(const bf16x8*)&Bs[((wn*4 + nj)*64 + lane)*8];
    #pragma unroll
    for (int mi = 0; mi < 4; mi++)
      #pragma unroll
      for (int nj = 0; nj < 4; nj++)
        acc[mi][nj] = __builtin_amdgcn_mfma_f32_16x16x32_bf16(av[mi], bv[nj], acc[mi][nj], 0, 0, 0);
    __syncthreads();
  }
  if constexpr (MODE == 0){
    const int ldc = gridDim.y * 128;
    #pragma unroll
    for (int mi = 0; mi < 4; mi++)
      #pragma unroll
      for (int nj = 0; nj < 4; nj++){
        int rm0 = blockIdx.x*128 + wm*64 + mi*16 + (lane >> 4) * 4;
        int cn  = blockIdx.y*128 + wn*64 + nj*16 + (lane & 15);
        #pragma unroll
        for (int j = 0; j < 4; j++)
          g.C[(size_t)(rm0 + j) * ldc + cn] = (short)f2bf(acc[mi][nj][j] * g.scale);
      }
  } else {
    #pragma unroll
    for (int mi = 0; mi < 4; mi++)
      #pragma unroll
      for (int nj = 0; nj < 4; nj++){
        int rm0 = blockIdx.x*128 + wm*64 + mi*16 + (lane >> 4) * 4;
        int cn  = blockIdx.y*128 + wn*64 + nj*16 + (lane & 15);
        #pragma unroll
        for (int j = 0; j < 4; j++){
          float base = acc[mi][nj][j] + s_bi[cn];
          #pragma unroll
          for (int c = 0; c < 8; c++)
            p.X[((size_t)(rm0 + j) * 8 + c) * 256 + cn] = (short)f2bf(base + s_emb[c*256 + cn]);
        }
      }
  }
}

// ---------------- fused layer: GEMM1 + attention + GEMM2 + residual + LN ----------------
// Block = 16 batches (128 X-rows). bufA: X frag-order -> y frag-order.
// bufB: Wqk panels (2x32KB dbuf) -> T row-major [128][260] -> Wvo panels -> residual.
// A-frag addr of element (r,c): ((r>>4)*8 + (c>>5))*512 + ((r&15) + 16*((c&31)>>3))*8 + (c&7)
__global__ __launch_bounds__(512, 1) void k_layer(short* Xg,
    const short* Wqk, const short* Wvo,
    const float* cq, const float* ck, const float* c0p, const float* cvo,
    const float* gv, const float* bv2){
  const int tid = threadIdx.x, lane = tid & 63, w = tid >> 6;
  const int wr = w >> 2, wc = w & 3;
  __shared__ alignas(16) short bufA[128*256];   // 64 KB
  __shared__ alignas(16) short bufB[128*260];   // 66.5 KB
  __shared__ float s_cq[256], s_ck[256], s_add[256], s_g[256], s_b[256];
  __shared__ float redS[4][128], redQ[4][128], s_mean[128], s_rstd[128];
  short* pan0 = bufB;
  short* pan1 = bufB + 16384;
  const int r0 = blockIdx.x * 128;
  // ---- prologue: stage X tile (frag-order) + Wqk panel0 + scalars ----
  #pragma unroll
  for (int i = 0; i < 8; i++){
    int s = w*8 + i, m16 = s >> 3, k32 = s & 7;
    gload16(Xg + (size_t)(r0 + m16*16 + (lane & 15)) * 256 + k32*32 + (lane >> 4)*8,
            &bufA[s*512]);
  }
  #pragma unroll
  for (int i = 0; i < 4; i++){
    int s = w*4 + i, n16 = s >> 1, kl = s & 1;
    gload16(Wqk + (size_t)(n16*16 + (lane & 15)) * 256 + kl*32 + (lane >> 4)*8,
            &pan0[s*512]);
  }
  if (tid < 256){
    s_cq[tid] = cq[tid]; s_ck[tid] = ck[tid];
    s_add[tid] = cvo[tid]; s_g[tid] = gv[tid]; s_b[tid] = bv2[tid];
  }
  const float c0 = c0p[0];
  __syncthreads();
  // ---- phase A: T = X @ Wqk ----
  f32x4 acc[4][4] = {};
  for (int kp = 0; kp < 4; kp++){
    short* cur = (kp & 1) ? pan1 : pan0;
    if (kp < 3){
      short* nxt = (kp & 1) ? pan0 : pan1;
      #pragma unroll
      for (int i = 0; i < 4; i++){
        int s = w*4 + i, n16 = s >> 1, kl = s & 1;
        gload16(Wqk + (size_t)(n16*16 + (lane & 15)) * 256 + (kp+1)*64 + kl*32 + (lane >> 4)*8,
                &nxt[s*512]);
      }
    }
    #pragma unroll
    for (int k2 = 0; k2 < 2; k2++){
      int kk = kp*2 + k2;
      bf16x8 av[4], bv[4];
      #pragma unroll
      for (int mi = 0; mi < 4; mi++)
        av[mi] = *(const bf16x8*)&bufA[(((wr*4 + mi)*8 + kk)*64 + lane)*8];
      #pragma unroll
      for (int nj = 0; nj < 4; nj++)
        bv[nj] = *(const bf16x8*)&cur[(((wc*4 + nj)*2 + k2)*64 + lane)*8];
      #pragma unroll
      for (int mi = 0; mi < 4; mi++)
        #pragma unroll
        for (int nj = 0; nj < 4; nj++)
          acc[mi][nj] = __builtin_amdgcn_mfma_f32_16x16x32_bf16(av[mi], bv[nj], acc[mi][nj], 0, 0, 0);
    }
    __syncthreads();
  }
  // ---- T acc -> bufB row-major [128][260] bf16 ----
  #pragma unroll
  for (int mi = 0; mi < 4; mi++)
    #pragma unroll
    for (int nj = 0; nj < 4; nj++){
      int rr = wr*64 + mi*16 + (lane >> 4)*4;
      int c  = wc*64 + nj*16 + (lane & 15);
      #pragma unroll
      for (int j = 0; j < 4; j++)
        bufB[(rr + j)*260 + c] = (short)f2bf(acc[mi][nj][j]);
    }
  __syncthreads();
  // ---- attention: 2 batches per wave ----
  const int n = lane >> 3, m = lane & 7;
  const unsigned long long MASK64 = 0x02191D69752B857EULL;
  const bool ok = (MASK64 >> lane) & 1ull;
  float yreg[2][4][8];
  #pragma unroll
  for (int bi = 0; bi < 2; bi++){
    int bl = w*2 + bi;
    int rn = bl*8 + n, rm = bl*8 + m;
    float s = 0.f;
    for (int d0 = 0; d0 < 256; d0 += 8){
      uint4 ta = *(const uint4*)&bufB[rn*260 + d0];
      uint4 xa = *(const uint4*)&bufA[(((rm>>4)*8 + (d0>>5))*64 + ((rm & 15) + 16*((d0>>3)&3)))*8];
      s = dot8(ta, xa, s);
    }
    float pq = 0.f, pk = 0.f;
    #pragma unroll
    for (int ii = 0; ii < 4; ii++){
      int c = m*32 + ii*8;
      uint4 xv = *(const uint4*)&bufA[(((rn>>4)*8 + m)*64 + ((rn & 15) + 16*ii))*8];
      float xf[8]; unpack8(xv, xf);
      #pragma unroll
      for (int j = 0; j < 8; j++){
        pq = fmaf(xf[j], s_cq[c + j], pq);
        pk = fmaf(xf[j], s_ck[c + j], pk);
      }
    }
    #pragma unroll
    for (int o = 1; o < 8; o <<= 1){ pq += __shfl_xor(pq, o); pk += __shfl_xor(pk, o); }
    float skm = __shfl(pk, (w & 0xffffff00) + (m << 3));  // lane m*8 within wave
    s = s + pq + skm + c0;
    float sv = ok ? s : -3.0e38f;
    float mx = sv;
    #pragma unroll
    for (int o = 1; o < 8; o <<= 1) mx = fmaxf(mx, __shfl_xor(mx, o));
    float e = ok ? __expf(sv - mx) : 0.f;
    float sum = e;
    #pragma unroll
    for (int o = 1; o < 8; o <<= 1) sum += __shfl_xor(sum, o);
    float at = e / sum;
    float am[8];
    #pragma unroll
    for (int mm = 0; mm < 8; mm++) am[mm] = __shfl(at, (n << 3) + mm);
    #pragma unroll
    for (int cb = 0; cb < 4; cb++){
      int d0 = m*8 + cb*64;
      float a8[8] = {0,0,0,0,0,0,0,0};
      #pragma unroll
      for (int mm = 0; mm < 8; mm++){
        int rrw = bl*8 + mm;
        uint4 xv = *(const uint4*)&bufA[(((rrw>>4)*8 + (d0>>5))*64 + ((rrw & 15) + 16*((d0>>3)&3)))*8];
        float xf[8]; unpack8(xv, xf);
        #pragma unroll
        for (int j = 0; j < 8; j++) a8[j] = fmaf(am[mm], xf[j], a8[j]);
      }
      #pragma unroll
      for (int j = 0; j < 8; j++) yreg[bi][cb][j] = a8[j];
    }
  }
  __syncthreads();   // all X reads done before y overwrites bufA
  #pragma unroll
  for (int bi = 0; bi < 2; bi++){
    int bl = w*2 + bi;
    int rn = bl*8 + n;
    #pragma unroll
    for (int cb = 0; cb < 4; cb++){
      int d0 = m*8 + cb*64;
      *(uint4*)&bufA[(((rn>>4)*8 + (d0>>5))*64 + ((rn & 15) + 16*((d0>>3)&3)))*8]
          = pack8(&yreg[bi][cb][0]);
    }
  }
  // ---- residual prefetch (coalesced, lands during phase C) ----
  uint4 resv[8];
  {
    const short* xr = Xg + (size_t)(r0 + (tid >> 2)) * 256 + (tid & 3)*64;
    #pragma unroll
    for (int i = 0; i < 8; i++) resv[i] = *(const uint4*)(xr + i*8);
  }
  // stage Wvo panel0
  #pragma unroll
  for (int i = 0; i < 4; i++){
    int s = w*4 + i, n16 = s >> 1, kl = s & 1;
    gload16(Wvo + (size_t)(n16*16 + (lane & 15)) * 256 + kl*32 + (lane >> 4)*8,
            &pan0[s*512]);
  }
  __syncthreads();   // y writes visible + panel0 ready
  // ---- phase C: out = y @ Wvo ----
  #pragma unroll
  for (int mi = 0; mi < 4; mi++)
    #pragma unroll
    for (int nj = 0; nj < 4; nj++)
      acc[mi][nj] = (f32x4){0.f, 0.f, 0.f, 0.f};
  for (int kp = 0; kp < 4; kp++){
    short* cur = (kp & 1) ? pan1 : pan0;
    if (kp < 3){
      short* nxt = (kp & 1) ? pan0 : pan1;
      #pragma unroll
      for (int i = 0; i < 4; i++){
        int s = w*4 + i, n16 = s >> 1, kl = s & 1;
        gload16(Wvo + (size_t)(n16*16 + (lane & 15)) * 256 + (kp+1)*64 + kl*32 + (lane >> 4)*8,
                &nxt[s*512]);
      }
    }
    #pragma unroll
    for (int k2 = 0; k2 < 2; k2++){
      int kk = kp*2 + k2;
      bf16x8 av[4], bv[4];
      #pragma unroll
      for (int mi = 0; mi < 4; mi++)
        av[mi] = *(const bf16x8*)&bufA[(((wr*4 + mi)*8 + kk)*64 + lane)*8];
      #pragma unroll
      for (int nj = 0; nj < 4; nj++)
        bv[nj] = *(const bf16x8*)&cur[(((wc*4 + nj)*2 + k2)*64 + lane)*8];
      #pragma unroll
      for (int mi = 0; mi < 4; mi++)
        #pragma unroll
        for (int nj = 0; nj < 4; nj++)
          acc[mi][nj] = __builtin_amdgcn_mfma_f32_16x16x32_bf16(av[mi], bv[nj], acc[mi][nj], 0, 0, 0);
    }
    __syncthreads();
  }
  // ---- residual regs -> bufB row-major [128][260] ----
  {
    int rrow = tid >> 2, cc0 = (tid & 3)*64;
    #pragma unroll
    for (int i = 0; i < 8; i++)
      *(uint4*)&bufB[rrow*260 + cc0 + i*8] = resv[i];
  }
  __syncthreads();
  // ---- epilogue: residual + LN (register-resident stats) ----
  #pragma unroll
  for (int mi = 0; mi < 4; mi++){
    #pragma unroll
    for (int j = 0; j < 4; j++){
      int rl = wr*64 + mi*16 + (lane >> 4)*4 + j;
      float ps = 0.f, pqq = 0.f;
      #pragma unroll
      for (int nj = 0; nj < 4; nj++){
        int c = wc*64 + nj*16 + (lane & 15);
        float t = acc[mi][nj][j] + s_add[c] + bfs(bufB[rl*260 + c]);
        acc[mi][nj][j] = t;
        ps += t; pqq = fmaf(t, t, pqq);
      }
      ps += __shfl_xor(ps, 1); pqq += __shfl_xor(pqq, 1);
      ps += __shfl_xor(ps, 2); pqq += __shfl_xor(pqq, 2);
      ps += __shfl_xor(ps, 4); pqq += __shfl_xor(pqq, 4);
      ps += __shfl_xor(ps, 8); pqq += __shfl_xor(pqq, 8);
      if ((lane & 15) == 0){ redS[wc][rl] = ps; redQ[wc][rl] = pqq; }
    }
  }
  __syncthreads();
  if (tid < 128){
    float sm = redS[0][tid] + redS[1][tid] + redS[2][tid] + redS[3][tid];
    float sq = redQ[0][tid] + redQ[1][tid] + redQ[2][tid] + redQ[3][tid];
    float mean = sm * (1.f/256.f);
    float var  = sq * (1.f/256.f) - mean * mean;
    s_mean[tid] = mean;
    s_rstd[tid] = rsqrtf(fmaxf(var, 0.f) + 1e-5f);
  }
  __syncthreads();
  #pragma unroll
  for (int mi = 0; mi < 4; mi++)
    #pragma unroll
    for (int j = 0; j < 4; j++){
      int rl = wr*64 + mi*16 + (lane >> 4)*4 + j;
      float mean = s_mean[rl], rstd = s_rstd[rl];
      #pragma unroll
      for (int nj = 0; nj < 4; nj++){
        int c = wc*64 + nj*16 + (lane & 15);
        float y = (acc[mi][nj][j] - mean) * rstd * s_g[c] + s_b[c];
        *(unsigned short*)(Xg + (size_t)(r0 + rl) * 256 + c) = f2bf(y);
      }
    }
}

// ---------------- GDP pre-reduce: Areg[b,:] = sum_c GDP[c] X[b,c,:] ----------------
__global__ __launch_bounds__(256) void k_reduce(const short* X, short* Areg){
  const float GDPc[8] = {0.4f,0.15f,0.12f,0.1f,0.08f,0.08f,0.05f,0.02f};
  int tid = threadIdx.x;
  int b = blockIdx.x*8 + (tid >> 5);
  int c0 = (tid & 31) * 8;
  float a8[8] = {0,0,0,0,0,0,0,0};
  #pragma unroll
  for (int cc = 0; cc < 8; cc++){
    uint4 xv = *(const uint4*)(X + ((size_t)b*8 + cc)*256 + c0);
    float xf[8]; unpack8(xv, xf);
    #pragma unroll
    for (int j = 0; j < 8; j++) a8[j] = fmaf(GDPc[cc], xf[j], a8[j]);
  }
  *(uint4*)(Areg + (size_t)b*256 + c0) = pack8(a8);
}

// ---------------- head: p = LN(Areg@Wp + bp); out = gelu_erf(p) ----------------
__global__ __launch_bounds__(512) void k_head(const short* Ax, const short* Bt,
    const float* addv, const float* gv, const float* bv2, float* outp){
  const int K = 256;
  const int tid = threadIdx.x, lane = tid & 63, w = tid >> 6;
  const int wr = w >> 2, wc = w & 3;
  __shared__ alignas(16) short As[128*32];
  __shared__ alignas(16) short Bs[256*32];
  __shared__ float redS[4][128], redQ[4][128];
  __shared__ float s_add[256], s_g[256], s_b[256];
  __shared__ float s_mean[128], s_rstd[128];
  if (tid < 256){ s_add[tid] = addv[tid]; s_g[tid] = gv[tid]; s_b[tid] = bv2[tid]; }
  const int r0 = blockIdx.x * 128;
  f32x4 acc[4][4] = {};
  for (int k0 = 0; k0 < K; k0 += 32){
    gload16(Ax + (size_t)(r0 + w*16 + (lane & 15)) * K + k0 + (lane >> 4)*8, &As[w*512]);
    #pragma unroll
    for (int i = 0; i < 2; i++){
      int s = w*2 + i;
      gload16(Bt + (size_t)(s*16 + (lane & 15)) * K + k0 + (lane >> 4)*8, &Bs[s*512]);
    }
    __syncthreads();
    bf16x8 av[4], bvv[4];
    #pragma unroll
    for (int mi = 0; mi < 4; mi++)
      av[mi] = *(const bf16x8*)&As[((wr*4 + mi)*64 + lane)*8];
    #pragma unroll
    for (int nj = 0; nj < 4; nj++)
      bvv[nj] = *(const bf16x8*)&Bs[((wc*4 + nj)*64 + lane)*8];
    #pragma unroll
    for (int mi = 0; mi < 4; mi++)
      #pragma unroll
      for (int nj = 0; nj < 4; nj++)
        acc[mi][nj] = __builtin_amdgcn_mfma_f32_16x16x32_bf16(av[mi], bvv[nj], acc[mi][nj], 0, 0, 0);
    __syncthreads();
  }
  #pragma unroll
  for (int mi = 0; mi < 4; mi++){
    #pragma unroll
    for (int j = 0; j < 4; j++){
      int rl = wr*64 + mi*16 + (lane >> 4)*4 + j;
      float ps = 0.f, pqq = 0.f;
      #pragma unroll
      for (int nj = 0; nj < 4; nj++){
        int c = wc*64 + nj*16 + (lane & 15);
        float t = acc[mi][nj][j] + s_add[c];
        acc[mi][nj][j] = t;
        ps += t; pqq = fmaf(t, t, pqq);
      }
      ps += __shfl_xor(ps, 1); pqq += __shfl_xor(pqq, 1);
      ps += __shfl_xor(ps, 2); pqq += __shfl_xor(pqq, 2);
      ps += __shfl_xor(ps, 4); pqq += __shfl_xor(pqq, 4);
      ps += __shfl_xor(ps, 8); pqq += __shfl_xor(pqq, 8);
      if ((lane & 15) == 0){ redS[wc][rl] = ps; redQ[wc][rl] = pqq; }
    }
  }
  __syncthreads();
  if (tid < 128){
    float sm = redS[0][tid] + redS[1][tid] + redS[2][tid] + redS[3][tid];
    float sq = redQ[0][tid] + redQ[1][tid] + redQ[2][tid] + redQ[3][tid];
    float mean = sm * (1.f/256.f);
    float var  = sq * (1.f/256.f) - mean * mean;
    s_mean[tid] = mean;
    s_rstd[tid] = rsqrtf(fmaxf(var, 0.f) + 1e-5f);
  }
  __syncthreads();
  #pragma unroll
  for (int mi = 0; mi < 4; mi++)
    #pragma unroll
    for (int j = 0; j < 4; j++){
      int rl = wr*64 + mi*16 + (lane >> 4)*4 + j;
      float mean = s_mean[rl], rstd = s_rstd[rl];
      #pragma unroll
      for (int nj = 0; nj < 4; nj++){
        int c = wc*64 + nj*16 + (lane & 15);
        float y = (acc[mi][nj][j] - mean) * rstd * s_g[c] + s_b[c];
        outp[(size_t)(r0 + rl) * 256 + c] = 0.5f * y * (1.0f + erff(y * 0.70710678118654752f));
      }
    }
}

extern "C" void kernel_launch(void* const* d_in, const int* in_sizes, int n_in,
                              void* d_out, int out_size, void* d_ws, size_t ws_size,
                              hipStream_t stream){
  (void)in_sizes; (void)n_in; (void)out_size; (void)ws_size;
  const float* rf  = (const float*)d_in[0];
  const float* Wi  = (const float*)d_in[1];
  const float* bi  = (const float*)d_in[2];
  const float* emb = (const float*)d_in[3];
  const float* Wq  = (const float*)d_in[4];
  const float* bq  = (const float*)d_in[5];
  const float* Wk  = (const float*)d_in[6];
  const float* bk  = (const float*)d_in[7];
  const float* Wv  = (const float*)d_in[8];
  const float* bv  = (const float*)d_in[9];
  const float* Wo  = (const float*)d_in[10];
  const float* bo  = (const float*)d_in[11];
  const float* lng = (const float*)d_in[12];
  const float* lnb = (const float*)d_in[13];
  const float* Wp  = (const float*)d_in[14];
  const float* bp  = (const float*)d_in[15];
  const float* lpg = (const float*)d_in[16];
  const float* lpb = (const float*)d_in[17];

  char* ws = (char*)d_ws;
  short* X    = (short*)(ws);                      // [65536][256] bf16
  // transient weight copies (consumed before X written)
  short* Wqb  = (short*)(ws);
  short* Wkb  = (short*)(ws + 1572864ull);
  short* Wvb  = (short*)(ws + 3145728ull);
  short* WoTb = (short*)(ws + 4718592ull);
  short* rfb  = (short*)(ws + 33554432ull);        // [8192][512] bf16 (pre-input GEMM)
  short* Areg = (short*)(ws + 33554432ull);        // [8192][256] bf16 (post-layers)
  // persistent tail
  short* WiTb = (short*)(ws + 67108864ull);
  short* WpTb = (short*)(ws + 67371008ull);
  short* Wqk  = (short*)(ws + 67502080ull);        // [3][256][256] Bt, pre-scaled 1/16
  short* Wvo  = (short*)(ws + 67895296ull);        // [3][256][256] Bt
  float* cqv  = (float*)(ws + 68288512ull);
  float* ckv  = (float*)(ws + 68291584ull);
  float* cvov = (float*)(ws + 68294656ull);
  float* c0v  = (float*)(ws + 68297728ull);

  { CvP cv;
    cv.src[0]=rf; cv.dst[0]=rfb;
    cv.src[1]=Wq; cv.dst[1]=Wqb;
    cv.src[2]=Wk; cv.dst[2]=Wkb;
    cv.src[3]=Wv; cv.dst[3]=Wvb;
    cv.boff[0]=0; cv.boff[1]=2048; cv.boff[2]=2432; cv.boff[3]=2816; cv.boff[4]=3200;
    k_convert<<<dim3(3200), dim3(256), 0, stream>>>(cv); }

  { TrP tp;
    tp.src[0]=Wi;          tp.dst[0]=WiTb;          tp.rows[0]=512;  tp.cols[0]=256;
    tp.src[1]=Wo;          tp.dst[1]=WoTb;          tp.rows[1]=1024; tp.cols[1]=256;
    tp.src[2]=Wo+262144;   tp.dst[2]=WoTb+262144;   tp.rows[2]=1024; tp.cols[2]=256;
    tp.src[3]=Wo+524288;   tp.dst[3]=WoTb+524288;   tp.rows[3]=1024; tp.cols[3]=256;
    tp.src[4]=Wp;          tp.dst[4]=WpTb;          tp.rows[4]=256;  tp.cols[4]=256;
    tp.toff[0]=0; tp.toff[1]=32; tp.toff[2]=96; tp.toff[3]=160; tp.toff[4]=224; tp.toff[5]=240;
    k_transpose<<<dim3(240), dim3(256), 0, stream>>>(tp); }

  k_vecs2<<<dim3(4, 3), dim3(256), 0, stream>>>(Wqb, Wkb, WoTb, bq, bk, bv, bo,
                                                cqv, ckv, cvov, c0v);

  { GemmP g{};
    for (int l = 0; l < 3; l++){
      g.d[l]   = GDesc{ Wkb  + l*262144, Wqb + l*262144, Wqk + l*65536, 1024, 0.0625f };
      g.d[3+l] = GDesc{ WoTb + l*262144, Wvb + l*262144, Wvo + l*65536, 1024, 1.0f };
    }
    k_gemm128<0><<<dim3(2,2,6), dim3(256), 0, stream>>>(g); }

  { GemmP g{};   // X[b,c,:] = rf@Wi + bi + emb[c]
    g.d[0] = GDesc{ rfb, WiTb, X, 512, 1.0f };
    g.bi = bi; g.emb = emb; g.X = X;
    k_gemm128<1><<<dim3(64,2,1), dim3(256), 0, stream>>>(g); }

  for (int l = 0; l < 3; l++)
    k_layer<<<dim3(512), dim3(512), 0, stream>>>(X, Wqk + l*65536, Wvo + l*65536,
        cqv + l*256, ckv + l*256, c0v + l, cvov + l*256, lng + l*256, lnb + l*256);

  k_reduce<<<dim3(1024), dim3(256), 0, stream>>>(X, Areg);
  k_head<<<dim3(64), dim3(512), 0, stream>>>(Areg, WpTb, bp, lpg, lpb, (float*)d_out);
}

// Round 6
// 373.210 us; speedup vs baseline: 1.3137x; 1.3137x over previous
//
#include <hip/hip_runtime.h>
#include <math.h>

// RegionalGNN: B=8192, NC=8, H=256, HD=1024, L=3.
// R6: k_layer rebuilt (R5 was latency-bound: 1 blk/CU, serial VALU attention, drain
//     barriers). Now: X in registers (A-frag layout), scores via MFMA (cq/c0 dropped
//     by softmax row-invariance; only skv=X.ck kept), PV via shfl from X-regs into
//     GEMM2 A-frags, weights streamed through a 4-slot global_load_lds ring with
//     counted vmcnt(2) + raw s_barrier (no drains). LDS 75.5KB -> 2 blocks/CU.

typedef short bf16x8 __attribute__((ext_vector_type(8)));
typedef float f32x4  __attribute__((ext_vector_type(4)));

__device__ __forceinline__ float bflo(unsigned int u){ return __uint_as_float(u << 16); }
__device__ __forceinline__ float bfhi(unsigned int u){ return __uint_as_float(u & 0xffff0000u); }
__device__ __forceinline__ float bfs(short s){ return __uint_as_float((unsigned int)(unsigned short)s << 16); }
__device__ __forceinline__ unsigned short f2bf(float f){
  unsigned int u = __float_as_uint(f);
  u += 0x7fffu + ((u >> 16) & 1u);          // RNE
  return (unsigned short)(u >> 16);
}
__device__ __forceinline__ void unpack8(uint4 a, float* o){
  o[0]=bflo(a.x); o[1]=bfhi(a.x); o[2]=bflo(a.y); o[3]=bfhi(a.y);
  o[4]=bflo(a.z); o[5]=bfhi(a.z); o[6]=bflo(a.w); o[7]=bfhi(a.w);
}
__device__ __forceinline__ uint4 pack8(const float* v){
  uint4 r;
  r.x = (unsigned int)f2bf(v[0]) | ((unsigned int)f2bf(v[1]) << 16);
  r.y = (unsigned int)f2bf(v[2]) | ((unsigned int)f2bf(v[3]) << 16);
  r.z = (unsigned int)f2bf(v[4]) | ((unsigned int)f2bf(v[5]) << 16);
  r.w = (unsigned int)f2bf(v[6]) | ((unsigned int)f2bf(v[7]) << 16);
  return r;
}
__device__ __forceinline__ float dot8(uint4 a, uint4 b, float s){
  s = fmaf(bflo(a.x), bflo(b.x), s); s = fmaf(bfhi(a.x), bfhi(b.x), s);
  s = fmaf(bflo(a.y), bflo(b.y), s); s = fmaf(bfhi(a.y), bfhi(b.y), s);
  s = fmaf(bflo(a.z), bflo(b.z), s); s = fmaf(bfhi(a.z), bfhi(b.z), s);
  s = fmaf(bflo(a.w), bflo(b.w), s); s = fmaf(bfhi(a.w), bfhi(b.w), s);
  return s;
}
__device__ __forceinline__ void gload16(const void* g, void* l){
  __builtin_amdgcn_global_load_lds(
      (const __attribute__((address_space(1))) unsigned int*)g,
      (__attribute__((address_space(3))) unsigned int*)l, 16, 0, 0);
}
__device__ __forceinline__ bf16x8 shfl8(bf16x8 v, int src){
  union U { bf16x8 h; int u[4]; };
  U a, r; a.h = v;
  #pragma unroll
  for (int j = 0; j < 4; j++) r.u[j] = __shfl(a.u[j], src);
  return r.h;
}
__device__ __forceinline__ bf16x8 pk8(const float* v){
  bf16x8 r;
  #pragma unroll
  for (int j = 0; j < 8; j++) r[j] = (short)f2bf(v[j]);
  return r;
}

// ---------------- convert f32 -> bf16 (rf, Wq, Wk, Wv) ----------------
struct CvP { const float* src[4]; short* dst[4]; int boff[5]; };
__global__ __launch_bounds__(256) void k_convert(CvP p){
  int bid = blockIdx.x, s = 0;
  while (bid >= p.boff[s+1]) s++;
  size_t e = (size_t)(bid - p.boff[s]) * 2048 + (size_t)threadIdx.x * 8;
  const float* src = p.src[s] + e;
  float4 v0 = *(const float4*)src;
  float4 v1 = *(const float4*)(src + 4);
  float v[8] = {v0.x,v0.y,v0.z,v0.w,v1.x,v1.y,v1.z,v1.w};
  *(uint4*)(p.dst[s] + e) = pack8(v);
}

// ---------------- transpose + convert (Wi, Wo x3, Wp) ----------------
struct TrP { const float* src[5]; short* dst[5]; int rows[5]; int cols[5]; int toff[6]; };
__global__ __launch_bounds__(256) void k_transpose(TrP p){
  __shared__ float tile[64][65];
  int bid = blockIdx.x, s = 0;
  while (bid >= p.toff[s+1]) s++;
  int ti = bid - p.toff[s];
  int cols = p.cols[s], rows = p.rows[s];
  int ntc = cols >> 6;
  int r0 = (ti / ntc) * 64, c0 = (ti % ntc) * 64;
  const float* src = p.src[s];
  int row = threadIdx.x >> 2, jb = (threadIdx.x & 3) * 16;
  #pragma unroll
  for (int j = 0; j < 16; j += 4){
    float4 v = *(const float4*)(src + (size_t)(r0 + row) * cols + c0 + jb + j);
    tile[row][jb+j] = v.x; tile[row][jb+j+1] = v.y; tile[row][jb+j+2] = v.z; tile[row][jb+j+3] = v.w;
  }
  __syncthreads();
  short* dst = p.dst[s];
  float tmp[16];
  #pragma unroll
  for (int j = 0; j < 16; j++) tmp[j] = tile[jb + j][row];
  #pragma unroll
  for (int j = 0; j < 16; j += 8)
    *(uint4*)(dst + (size_t)(c0 + row) * rows + r0 + jb + j) = pack8(&tmp[j]);
}

// ---------------- bias-fold vectors via bf16 row-dots ----------------
__global__ __launch_bounds__(256) void k_vecs2(
    const short* Wqb, const short* Wkb, const short* WoTb,
    const float* bq, const float* bk, const float* bv, const float* bo,
    float* cq, float* ck, float* cvo, float* c0){
  const int job = blockIdx.x, l = blockIdx.y, tid = threadIdx.x;
  __shared__ float sv[1024];
  __shared__ float red[256];
  if (job == 3){
    float pp = 0.f;
    #pragma unroll
    for (int i = 0; i < 4; i++){
      int d = tid*4 + i;
      pp = fmaf(bq[l*1024 + d], bk[l*1024 + d], pp);
    }
    red[tid] = pp; __syncthreads();
    for (int o = 128; o > 0; o >>= 1){ if (tid < o) red[tid] += red[tid + o]; __syncthreads(); }
    if (tid == 0) c0[l] = red[0] * 0.0625f;
    return;
  }
  const short* rows = (job==0 ? Wqb : job==1 ? Wkb : WoTb) + (size_t)l*262144;
  const float* vecg = (job==0 ? bk : job==1 ? bq : bv) + l*1024;
  const float scale = (job == 2) ? 1.0f : 0.0625f;
  for (int i = tid; i < 1024; i += 256) sv[i] = vecg[i];
  __syncthreads();
  const int row = tid >> 3, sub = tid & 7;
  for (int pass = 0; pass < 8; pass++){
    int r = pass*32 + row;
    const short* rp = rows + (size_t)r*1024;
    float acc = 0.f;
    #pragma unroll
    for (int i = 0; i < 16; i++){
      int d = sub*8 + i*64;
      uint4 v = *(const uint4*)(rp + d);
      float f[8]; unpack8(v, f);
      #pragma unroll
      for (int j = 0; j < 8; j++) acc = fmaf(f[j], sv[d + j], acc);
    }
    acc += __shfl_xor(acc, 1); acc += __shfl_xor(acc, 2); acc += __shfl_xor(acc, 4);
    if (sub == 0){
      float o = acc * scale;
      if (job == 2) o += bo[l*256 + r];
      (job==0 ? cq : job==1 ? ck : cvo)[l*256 + r] = o;
    }
  }
}

// ---------------- 128x128 MFMA GEMM (precompute + input projection) ----------------
struct GDesc { const short* A; const short* Bt; short* C; int K; float scale; };
struct GemmP { GDesc d[6]; const float* bi; const float* emb; short* X; };
template<int MODE>
__global__ __launch_bounds__(256) void k_gemm128(GemmP p){
  GDesc g = p.d[blockIdx.z];
  const int tid = threadIdx.x, lane = tid & 63, w = tid >> 6;
  const int wm = w >> 1, wn = w & 1;
  __shared__ alignas(16) short As[128*32];
  __shared__ alignas(16) short Bs[128*32];
  __shared__ float s_bi[256];
  __shared__ float s_emb[2048];
  if constexpr (MODE == 1){
    s_bi[tid] = p.bi[tid];
    for (int i = tid; i < 2048; i += 256) s_emb[i] = p.emb[i];
  }
  const int K = g.K;
  const short* Ab = g.A + (size_t)blockIdx.x * 128 * K;
  const short* Bb = g.Bt + (size_t)blockIdx.y * 128 * K;
  f32x4 acc[4][4] = {};
  for (int k0 = 0; k0 < K; k0 += 32){
    #pragma unroll
    for (int i = 0; i < 2; i++){
      int s = w*2 + i;
      int ro = (s >> 2)*64 + (s & 3)*16 + (lane & 15);
      int co = k0 + (lane >> 4) * 8;
      gload16(Ab + (size_t)ro * K + co, &As[s*512]);
      gload16(Bb + (size_t)ro * K + co, &Bs[s*512]);
    }
    __syncthreads();
    bf16x8 av[4], bv[4];
    #pragma unroll
    for (int mi = 0; mi < 4; mi++)
      av[mi] = *(const bf16x8*)&As[((wm*4 + mi)*64 + lane)*8];
    #pragma unroll
    for (int nj = 0; nj < 4; nj++)
      bv[nj] = *(const bf16x8*)&Bs[((wn*4 + nj)*64 + lane)*8];
    #pragma unroll
    for (int mi = 0; mi < 4; mi++)
      #pragma unroll
      for (int nj = 0; nj < 4; nj++)
        acc[mi][nj] = __builtin_amdgcn_mfma_f32_16x16x32_bf16(av[mi], bv[nj], acc[mi][nj], 0, 0, 0);
    __syncthreads();
  }
  if constexpr (MODE == 0){
    const int ldc = gridDim.y * 128;
    #pragma unroll
    for (int mi = 0; mi < 4; mi++)
      #pragma unroll
      for (int nj = 0; nj < 4; nj++){
        int rm0 = blockIdx.x*128 + wm*64 + mi*16 + (lane >> 4) * 4;
        int cn  = blockIdx.y*128 + wn*64 + nj*16 + (lane & 15);
        #pragma unroll
        for (int j = 0; j < 4; j++)
          g.C[(size_t)(rm0 + j) * ldc + cn] = (short)f2bf(acc[mi][nj][j] * g.scale);
      }
  } else {
    #pragma unroll
    for (int mi = 0; mi < 4; mi++)
      #pragma unroll
      for (int nj = 0; nj < 4; nj++){
        int rm0 = blockIdx.x*128 + wm*64 + mi*16 + (lane >> 4) * 4;
        int cn  = blockIdx.y*128 + wn*64 + nj*16 + (lane & 15);
        #pragma unroll
        for (int j = 0; j < 4; j++){
          float base = acc[mi][nj][j] + s_bi[cn];
          #pragma unroll
          for (int c = 0; c < 8; c++)
            p.X[((size_t)(rm0 + j) * 8 + c) * 256 + cn] = (short)f2bf(base + s_emb[c*256 + cn]);
        }
      }
  }
}

// ---------------- fused layer (R6) ----------------
// Block = 16 batches (128 rows), wave = batch-pair p=w. X in regs (A-frag layout).
// T used ONLY for scores; scores s[n,m] = T[n].X[m] + skv[m] (cq/c0 softmax-invariant).
// Weights: 32 panels (Wqk h0 k0-7, Wqk h1, Wvo h0, Wvo h1) through 4-slot ring,
// counted vmcnt(2) + raw s_barrier -- no vmcnt(0) drains in the loop.
__global__ __launch_bounds__(512, 4) void k_layer(short* __restrict__ Xg,
    const short* __restrict__ Wqk, const short* __restrict__ Wvo,
    const float* __restrict__ ckp, const float* __restrict__ cvop,
    const float* __restrict__ gp, const float* __restrict__ bp){
  const int tid = threadIdx.x, lane = tid & 63, w = tid >> 6;
  __shared__ alignas(16) short pan[4][4096];   // 32 KB ring (4 x 8KB panels)
  __shared__ alignas(16) short tst[8][2048];   // 32 KB: per-pair T-half frags / LN stash
  __shared__ alignas(16) float atn[8][16][16]; // 8 KB attention probs
  __shared__ short ckb[256];
  __shared__ float s_add[256], s_g[256], s_b[256];
  const int r0 = blockIdx.x * 128;
  const int dsub = (lane >> 4) * 8;

  // X rows -> registers: lane holds X[row = pair*16 + (lane&15)][dsub + e + 32c]
  bf16x8 xf[8];
  { const short* xp = Xg + (size_t)(r0 + w*16 + (lane & 15)) * 256 + dsub;
    #pragma unroll
    for (int c = 0; c < 8; c++) xf[c] = *(const bf16x8*)(xp + c*32); }
  if (tid < 256){
    ckb[tid]   = (short)f2bf(ckp[tid]);
    s_add[tid] = cvop[tid]; s_g[tid] = gp[tid]; s_b[tid] = bp[tid];
  }

  #define VMW2 asm volatile("s_waitcnt vmcnt(2)" ::: "memory")
  #define VMW1 asm volatile("s_waitcnt vmcnt(1)" ::: "memory")
  #define VMW0 asm volatile("s_waitcnt vmcnt(0)" ::: "memory")
  #define LKW  asm volatile("s_waitcnt lgkmcnt(0)" ::: "memory")
  #define BAR  __builtin_amdgcn_s_barrier()

  auto STAGE = [&](int i){
    const short* W = (i < 16) ? Wqk : Wvo;
    int loc = i & 15;                                  // h = loc>>3, kk = loc&7
    const short* src = W + (size_t)((loc >> 3)*128 + w*16 + (lane & 15)) * 256
                         + (loc & 7)*32 + dsub;
    gload16(src, &pan[i & 3][w * 512]);
  };
  STAGE(0); STAGE(1); STAGE(2);
  LKW;   // publish ckb/s_* before first barrier

  f32x4 acc[8];
  f32x4 sacc = {0.f, 0.f, 0.f, 0.f};

  // ===== GEMM1: T = X @ Wqk (N-halves), scores accumulate per half =====
  #pragma unroll
  for (int h = 0; h < 2; h++){
    #pragma unroll
    for (int nj = 0; nj < 8; nj++) acc[nj] = (f32x4){0.f,0.f,0.f,0.f};
    #pragma unroll
    for (int kk = 0; kk < 8; kk++){
      const int i = h*8 + kk;
      VMW2; BAR;
      STAGE(i + 3);
      const short* P = pan[i & 3];
      #pragma unroll
      for (int nj = 0; nj < 8; nj++){
        bf16x8 bv = *(const bf16x8*)&P[(nj*64 + lane)*8];
        acc[nj] = __builtin_amdgcn_mfma_f32_16x16x32_bf16(xf[kk], bv, acc[nj], 0, 0, 0);
      }
    }
    // T-half -> wave-private LDS in A-frag order
    #pragma unroll
    for (int nj = 0; nj < 8; nj++)
      #pragma unroll
      for (int jj = 0; jj < 4; jj++){
        int i_ = (lane >> 4)*4 + jj, nl = nj*16 + (lane & 15);
        tst[w][(nl >> 5)*512 + (i_ + 16*((nl >> 3) & 3))*8 + (nl & 7)] = (short)f2bf(acc[nj][jj]);
      }
    LKW;
    #pragma unroll
    for (int cl = 0; cl < 4; cl++){
      bf16x8 tf = *(const bf16x8*)&tst[w][cl*512 + lane*8];
      sacc = __builtin_amdgcn_mfma_f32_16x16x32_bf16(tf, xf[h*4 + cl], sacc, 0, 0, 0);
    }
  }

  // ===== skv[m] = X[m].ck (m = lane&15), reduce partial d-quarters =====
  float skv = 0.f;
  #pragma unroll
  for (int c = 0; c < 8; c++){
    bf16x8 cv = *(const bf16x8*)&ckb[c*32 + dsub];
    #pragma unroll
    for (int e = 0; e < 8; e++) skv = fmaf(bfs(xf[c][e]), bfs(cv[e]), skv);
  }
  skv += __shfl_xor(skv, 16); skv += __shfl_xor(skv, 32);

  // ===== softmax (C-layout: row i_=(lane>>4)*4+jj, col j_=lane&15) =====
  {
    const unsigned long long MASK64 = 0x02191D69752B857EULL;   // ADJ[n][m] at bit n*8+m
    #pragma unroll
    for (int jj = 0; jj < 4; jj++){
      int i_ = (lane >> 4)*4 + jj, j_ = lane & 15;
      bool ok = (((i_ ^ j_) & 8) == 0) &&
                ((MASK64 >> (((i_ & 7) << 3) | (j_ & 7))) & 1ull);
      float sv = ok ? (sacc[jj] + skv) : -3.0e38f;
      float mx = sv;
      mx = fmaxf(mx, __shfl_xor(mx, 1));
      mx = fmaxf(mx, __shfl_xor(mx, 2));
      mx = fmaxf(mx, __shfl_xor(mx, 4));
      float e = ok ? __expf(sv - mx) : 0.f;
      float sum = e;
      sum += __shfl_xor(sum, 1); sum += __shfl_xor(sum, 2); sum += __shfl_xor(sum, 4);
      atn[w][i_][j_] = e / sum;
    }
  }
  LKW;   // own-wave atn writes -> reads

  // ===== PV: y[r=lane&15][dsub+e+32c] = sum_m attn[r][m] X[m][d], X via shfl =====
  bf16x8 yfrag[8];
  {
    float4 A0 = *(const float4*)&atn[w][lane & 15][lane & 8];
    float4 A1 = *(const float4*)&atn[w][lane & 15][(lane & 8) + 4];
    float am[8] = {A0.x, A0.y, A0.z, A0.w, A1.x, A1.y, A1.z, A1.w};
    #pragma unroll
    for (int c = 0; c < 8; c++){
      float a8[8] = {0,0,0,0,0,0,0,0};
      #pragma unroll
      for (int mi = 0; mi < 8; mi++){
        bf16x8 xs = shfl8(xf[c], (lane & 48) | (lane & 8) | mi);
        #pragma unroll
        for (int e = 0; e < 8; e++) a8[e] = fmaf(am[mi], bfs(xs[e]), a8[e]);
      }
      yfrag[c] = pk8(a8);
    }
  }

  // ===== GEMM2: out = y @ Wvo (N-halves) + cvo + residual + LN =====
  float rs[4] = {0,0,0,0}, rq[4] = {0,0,0,0};
  #pragma unroll
  for (int h = 0; h < 2; h++){
    #pragma unroll
    for (int nj = 0; nj < 8; nj++) acc[nj] = (f32x4){0.f,0.f,0.f,0.f};
    #pragma unroll
    for (int kk = 0; kk < 8; kk++){
      const int i = 16 + h*8 + kk;
      if (i <= 29) { VMW2; } else if (i == 30) { VMW1; } else { VMW0; }
      BAR;
      if (i + 3 <= 31) STAGE(i + 3);
      const short* P = pan[i & 3];
      #pragma unroll
      for (int nj = 0; nj < 8; nj++){
        bf16x8 bv = *(const bf16x8*)&P[(nj*64 + lane)*8];
        acc[nj] = __builtin_amdgcn_mfma_f32_16x16x32_bf16(yfrag[kk], bv, acc[nj], 0, 0, 0);
      }
    }
    #pragma unroll
    for (int jj = 0; jj < 4; jj++){
      const int i_ = (lane >> 4)*4 + jj;
      const size_t rb = (size_t)(r0 + w*16 + i_) * 256;
      float ps = 0.f, pq = 0.f;
      #pragma unroll
      for (int nj = 0; nj < 8; nj++){
        int n = h*128 + nj*16 + (lane & 15);
        unsigned short rv = *(const unsigned short*)(Xg + rb + n);
        float t = acc[nj][jj] + s_add[n] + __uint_as_float((unsigned int)rv << 16);
        acc[nj][jj] = t;
        ps += t; pq = fmaf(t, t, pq);
      }
      ps += __shfl_xor(ps, 1); ps += __shfl_xor(ps, 2);
      ps += __shfl_xor(ps, 4); ps += __shfl_xor(ps, 8);
      pq += __shfl_xor(pq, 1); pq += __shfl_xor(pq, 2);
      pq += __shfl_xor(pq, 4); pq += __shfl_xor(pq, 8);
      rs[jj] += ps; rq[jj] += pq;
      if (h == 0){
        #pragma unroll
        for (int nj = 0; nj < 8; nj++)
          tst[w][i_*128 + nj*16 + (lane & 15)] = (short)f2bf(acc[nj][jj]);
      } else {
        float mean_ = rs[jj] * (1.f/256.f);
        float var_  = rq[jj] * (1.f/256.f) - mean_ * mean_;
        float rst_  = rsqrtf(fmaxf(var_, 0.f) + 1e-5f);
        #pragma unroll
        for (int nj = 0; nj < 8; nj++){
          int n = 128 + nj*16 + (lane & 15);
          float yv = (acc[nj][jj] - mean_) * rst_ * s_g[n] + s_b[n];
          *(unsigned short*)(Xg + rb + n) = f2bf(yv);
        }
        LKW;
        #pragma unroll
        for (int nj = 0; nj < 8; nj++){
          int n = nj*16 + (lane & 15);
          float t = bfs(tst[w][i_*128 + n]);
          float yv = (t - mean_) * rst_ * s_g[n] + s_b[n];
          *(unsigned short*)(Xg + rb + n) = f2bf(yv);
        }
      }
    }
  }
  #undef VMW2
  #undef VMW1
  #undef VMW0
  #undef LKW
  #undef BAR
}

// ---------------- GDP pre-reduce: Areg[b,:] = sum_c GDP[c] X[b,c,:] ----------------
__global__ __launch_bounds__(256) void k_reduce(const short* X, short* Areg){
  const float GDPc[8] = {0.4f,0.15f,0.12f,0.1f,0.08f,0.08f,0.05f,0.02f};
  int tid = threadIdx.x;
  int b = blockIdx.x*8 + (tid >> 5);
  int c0 = (tid & 31) * 8;
  float a8[8] = {0,0,0,0,0,0,0,0};
  #pragma unroll
  for (int cc = 0; cc < 8; cc++){
    uint4 xv = *(const uint4*)(X + ((size_t)b*8 + cc)*256 + c0);
    float xf[8]; unpack8(xv, xf);
    #pragma unroll
    for (int j = 0; j < 8; j++) a8[j] = fmaf(GDPc[cc], xf[j], a8[j]);
  }
  *(uint4*)(Areg + (size_t)b*256 + c0) = pack8(a8);
}

// ---------------- head: p = LN(Areg@Wp + bp); out = gelu_erf(p) ----------------
__global__ __launch_bounds__(512) void k_head(const short* Ax, const short* Bt,
    const float* addv, const float* gv, const float* bv2, float* outp){
  const int K = 256;
  const int tid = threadIdx.x, lane = tid & 63, w = tid >> 6;
  const int wr = w >> 2, wc = w & 3;
  __shared__ alignas(16) short As[128*32];
  __shared__ alignas(16) short Bs[256*32];
  __shared__ float redS[4][128], redQ[4][128];
  __shared__ float s_add[256], s_g[256], s_b[256];
  __shared__ float s_mean[128], s_rstd[128];
  if (tid < 256){ s_add[tid] = addv[tid]; s_g[tid] = gv[tid]; s_b[tid] = bv2[tid]; }
  const int r0 = blockIdx.x * 128;
  f32x4 acc[4][4] = {};
  for (int k0 = 0; k0 < K; k0 += 32){
    gload16(Ax + (size_t)(r0 + w*16 + (lane & 15)) * K + k0 + (lane >> 4)*8, &As[w*512]);
    #pragma unroll
    for (int i = 0; i < 2; i++){
      int s = w*2 + i;
      gload16(Bt + (size_t)(s*16 + (lane & 15)) * K + k0 + (lane >> 4)*8, &Bs[s*512]);
    }
    __syncthreads();
    bf16x8 av[4], bvv[4];
    #pragma unroll
    for (int mi = 0; mi < 4; mi++)
      av[mi] = *(const bf16x8*)&As[((wr*4 + mi)*64 + lane)*8];
    #pragma unroll
    for (int nj = 0; nj < 4; nj++)
      bvv[nj] = *(const bf16x8*)&Bs[((wc*4 + nj)*64 + lane)*8];
    #pragma unroll
    for (int mi = 0; mi < 4; mi++)
      #pragma unroll
      for (int nj = 0; nj < 4; nj++)
        acc[mi][nj] = __builtin_amdgcn_mfma_f32_16x16x32_bf16(av[mi], bvv[nj], acc[mi][nj], 0, 0, 0);
    __syncthreads();
  }
  #pragma unroll
  for (int mi = 0; mi < 4; mi++){
    #pragma unroll
    for (int j = 0; j < 4; j++){
      int rl = wr*64 + mi*16 + (lane >> 4)*4 + j;
      float ps = 0.f, pqq = 0.f;
      #pragma unroll
      for (int nj = 0; nj < 4; nj++){
        int c = wc*64 + nj*16 + (lane & 15);
        float t = acc[mi][nj][j] + s_add[c];
        acc[mi][nj][j] = t;
        ps += t; pqq = fmaf(t, t, pqq);
      }
      ps += __shfl_xor(ps, 1); pqq += __shfl_xor(pqq, 1);
      ps += __shfl_xor(ps, 2); pqq += __shfl_xor(pqq, 2);
      ps += __shfl_xor(ps, 4); pqq += __shfl_xor(pqq, 4);
      ps += __shfl_xor(ps, 8); pqq += __shfl_xor(pqq, 8);
      if ((lane & 15) == 0){ redS[wc][rl] = ps; redQ[wc][rl] = pqq; }
    }
  }
  __syncthreads();
  if (tid < 128){
    float sm = redS[0][tid] + redS[1][tid] + redS[2][tid] + redS[3][tid];
    float sq = redQ[0][tid] + redQ[1][tid] + redQ[2][tid] + redQ[3][tid];
    float mean = sm * (1.f/256.f);
    float var  = sq * (1.f/256.f) - mean * mean;
    s_mean[tid] = mean;
    s_rstd[tid] = rsqrtf(fmaxf(var, 0.f) + 1e-5f);
  }
  __syncthreads();
  #pragma unroll
  for (int mi = 0; mi < 4; mi++)
    #pragma unroll
    for (int j = 0; j < 4; j++){
      int rl = wr*64 + mi*16 + (lane >> 4)*4 + j;
      float mean = s_mean[rl], rstd = s_rstd[rl];
      #pragma unroll
      for (int nj = 0; nj < 4; nj++){
        int c = wc*64 + nj*16 + (lane & 15);
        float y = (acc[mi][nj][j] - mean) * rstd * s_g[c] + s_b[c];
        outp[(size_t)(r0 + rl) * 256 + c] = 0.5f * y * (1.0f + erff(y * 0.70710678118654752f));
      }
    }
}

extern "C" void kernel_launch(void* const* d_in, const int* in_sizes, int n_in,
                              void* d_out, int out_size, void* d_ws, size_t ws_size,
                              hipStream_t stream){
  (void)in_sizes; (void)n_in; (void)out_size; (void)ws_size;
  const float* rf  = (const float*)d_in[0];
  const float* Wi  = (const float*)d_in[1];
  const float* bi  = (const float*)d_in[2];
  const float* emb = (const float*)d_in[3];
  const float* Wq  = (const float*)d_in[4];
  const float* bq  = (const float*)d_in[5];
  const float* Wk  = (const float*)d_in[6];
  const float* bk  = (const float*)d_in[7];
  const float* Wv  = (const float*)d_in[8];
  const float* bv  = (const float*)d_in[9];
  const float* Wo  = (const float*)d_in[10];
  const float* bo  = (const float*)d_in[11];
  const float* lng = (const float*)d_in[12];
  const float* lnb = (const float*)d_in[13];
  const float* Wp  = (const float*)d_in[14];
  const float* bp  = (const float*)d_in[15];
  const float* lpg = (const float*)d_in[16];
  const float* lpb = (const float*)d_in[17];

  char* ws = (char*)d_ws;
  short* X    = (short*)(ws);                      // [65536][256] bf16
  // transient weight copies (consumed before X written)
  short* Wqb  = (short*)(ws);
  short* Wkb  = (short*)(ws + 1572864ull);
  short* Wvb  = (short*)(ws + 3145728ull);
  short* WoTb = (short*)(ws + 4718592ull);
  short* rfb  = (short*)(ws + 33554432ull);        // [8192][512] bf16 (pre-input GEMM)
  short* Areg = (short*)(ws + 33554432ull);        // [8192][256] bf16 (post-layers)
  // persistent tail
  short* WiTb = (short*)(ws + 67108864ull);
  short* WpTb = (short*)(ws + 67371008ull);
  short* Wqk  = (short*)(ws + 67502080ull);        // [3][256][256] Bt, pre-scaled 1/16
  short* Wvo  = (short*)(ws + 67895296ull);        // [3][256][256] Bt
  float* cqv  = (float*)(ws + 68288512ull);
  float* ckv  = (float*)(ws + 68291584ull);
  float* cvov = (float*)(ws + 68294656ull);
  float* c0v  = (float*)(ws + 68297728ull);

  { CvP cv;
    cv.src[0]=rf; cv.dst[0]=rfb;
    cv.src[1]=Wq; cv.dst[1]=Wqb;
    cv.src[2]=Wk; cv.dst[2]=Wkb;
    cv.src[3]=Wv; cv.dst[3]=Wvb;
    cv.boff[0]=0; cv.boff[1]=2048; cv.boff[2]=2432; cv.boff[3]=2816; cv.boff[4]=3200;
    k_convert<<<dim3(3200), dim3(256), 0, stream>>>(cv); }

  { TrP tp;
    tp.src[0]=Wi;          tp.dst[0]=WiTb;          tp.rows[0]=512;  tp.cols[0]=256;
    tp.src[1]=Wo;          tp.dst[1]=WoTb;          tp.rows[1]=1024; tp.cols[1]=256;
    tp.src[2]=Wo+262144;   tp.dst[2]=WoTb+262144;   tp.rows[2]=1024; tp.cols[2]=256;
    tp.src[3]=Wo+524288;   tp.dst[3]=WoTb+524288;   tp.rows[3]=1024; tp.cols[3]=256;
    tp.src[4]=Wp;          tp.dst[4]=WpTb;          tp.rows[4]=256;  tp.cols[4]=256;
    tp.toff[0]=0; tp.toff[1]=32; tp.toff[2]=96; tp.toff[3]=160; tp.toff[4]=224; tp.toff[5]=240;
    k_transpose<<<dim3(240), dim3(256), 0, stream>>>(tp); }

  k_vecs2<<<dim3(4, 3), dim3(256), 0, stream>>>(Wqb, Wkb, WoTb, bq, bk, bv, bo,
                                                cqv, ckv, cvov, c0v);

  { GemmP g{};
    for (int l = 0; l < 3; l++){
      g.d[l]   = GDesc{ Wkb  + l*262144, Wqb + l*262144, Wqk + l*65536, 1024, 0.0625f };
      g.d[3+l] = GDesc{ WoTb + l*262144, Wvb + l*262144, Wvo + l*65536, 1024, 1.0f };
    }
    k_gemm128<0><<<dim3(2,2,6), dim3(256), 0, stream>>>(g); }

  { GemmP g{};   // X[b,c,:] = rf@Wi + bi + emb[c]
    g.d[0] = GDesc{ rfb, WiTb, X, 512, 1.0f };
    g.bi = bi; g.emb = emb; g.X = X;
    k_gemm128<1><<<dim3(64,2,1), dim3(256), 0, stream>>>(g); }

  for (int l = 0; l < 3; l++)
    k_layer<<<dim3(512), dim3(512), 0, stream>>>(X, Wqk + l*65536, Wvo + l*65536,
        ckv + l*256, cvov + l*256, lng + l*256, lnb + l*256);

  k_reduce<<<dim3(1024), dim3(256), 0, stream>>>(X, Areg);
  k_head<<<dim3(64), dim3(512), 0, stream>>>(Areg, WpTb, bp, lpg, lpb, (float*)d_out);
}